// Round 8
// baseline (116.746 us; speedup 1.0000x reference)
//
#include <hip/hip_runtime.h>

// RBFNN fused, round 8: M=64 per block (8 waves) — halve per-CU frag traffic.
// out[B,K] = exp(-gamma * dist(x, centers)) @ W^T + b
// B=16384, F=512, C=1024, K=100.
//
// R7 accounting: G1 is L2-BW-bound on B frags (32KB/stage/CU vs ~56B/cyc L2
// supply -> ~585cyc/stage vs 148cyc MFMA floor); per-CU frag traffic 1.5MB
// because 2 co-resident 32-row blocks read the SAME cb2/wb2. Fix: 64-row
// blocks, 512 thr (8 waves), grid 256 = 1 block/CU. Unique B/CU 1MB->512KB
// (intra-block x2 read of B frags is L1-resident: 16KB stage set << 32KB L1);
// W 512->256KB with zero duplication (8 waves x 1 kout-frag). Same 1-barrier
// -per-chunk skeleton (6 barriers; no cross-block cover costs ~1us, traffic
// saves ~6us). G1 wave=(h=row half, g=col group), acc1[2][4]; G2 wave owns
// kout frag wv, acc2[4]. LDS 102KB (x 34 + phi dbuf 68), VGPR ~180.

#define NB 16384
#define NF 512
#define NC 1024
#define NK 100

#define A_PITCH 528   // bytes/row (512 fp8 + 16 pad)
#define P_PITCH 264   // shorts/row (256 bf16 + 8 pad)

#define CB_BYTES (NC * NF)      // 512KB fp8 centers, fragment-ordered
#define WB_BYTES (256 * 1024)   // 256KB bf16 W (100->128 kouts), frag-ordered
#define WS_NEED (CB_BYTES + NC * 4 + WB_BYTES)

typedef __attribute__((ext_vector_type(8))) short short8;
typedef __attribute__((ext_vector_type(4))) short short4v;
typedef __attribute__((ext_vector_type(4))) float f4;
typedef __attribute__((ext_vector_type(4))) unsigned int uint4v;
typedef __attribute__((ext_vector_type(2))) unsigned long ulong2v;
typedef unsigned short ushort;
typedef unsigned int uint;

__device__ __forceinline__ short bf16t(float f) {
  return (short)(__float_as_uint(f) >> 16);
}

__device__ __forceinline__ uint pk4_fp8(float a, float b, float c, float d) {
  uint r = __builtin_amdgcn_cvt_pk_fp8_f32(a, b, 0, false);
  return __builtin_amdgcn_cvt_pk_fp8_f32(c, d, r, true);
}

// ---------------- merged prepass (unchanged layouts from R6/R7) ----------------
__global__ __launch_bounds__(256) void prep_all(
    const float* __restrict__ ctr, const float* __restrict__ W,
    char* __restrict__ cb, float* __restrict__ csq, char* __restrict__ wb) {
  if (blockIdx.x < 32) {
    const int t = blockIdx.x * 256 + threadIdx.x;  // 0..8191
    const int cg = t >> 3;                          // center row 0..1023
    const int kb = t & 7;
    const f4* src = (const f4*)(ctr + (size_t)cg * NF + kb * 64);
    float f[64];
    float ss = 0.f;
#pragma unroll
    for (int i = 0; i < 16; ++i) {
      f4 v = src[i];
      f[4 * i] = v.x; f[4 * i + 1] = v.y; f[4 * i + 2] = v.z; f[4 * i + 3] = v.w;
      ss += v.x * v.x + v.y * v.y + v.z * v.z + v.w * v.w;
    }
    uint w[16];
#pragma unroll
    for (int m = 0; m < 16; ++m)
      w[m] = pk4_fp8(f[4 * m], f[4 * m + 1], f[4 * m + 2], f[4 * m + 3]);
    const int c = cg >> 8, fr = (cg >> 4) & 15, lm = cg & 15;
    char* base = cb + (size_t)((c * 8 + kb) * 16 + fr) * 1024 + lm * 16;
#pragma unroll
    for (int lg = 0; lg < 4; ++lg) {
      uint4v u = {w[2 * lg], w[2 * lg + 1], w[8 + 2 * lg], w[9 + 2 * lg]};
      *(uint4v*)(base + lg * 256) = u;
    }
    ss += __shfl_down(ss, 4, 64);
    ss += __shfl_down(ss, 2, 64);
    ss += __shfl_down(ss, 1, 64);
    if (kb == 0) csq[cg] = ss;
  } else {
    const int t = (blockIdx.x - 32) * 256 + threadIdx.x;  // 0..511
    const int kout = t >> 2, c = t & 3;
    const int kf = kout >> 4, lm = kout & 15;
#pragma unroll
    for (int ks = 0; ks < 8; ++ks) {
#pragma unroll
      for (int lg = 0; lg < 4; ++lg) {
        short4v h0 = {0, 0, 0, 0}, h1 = {0, 0, 0, 0};
        if (kout < NK) {
          const float* src = W + (size_t)kout * NC + c * 256 + ks * 32 + lg * 8;
          f4 v0 = ((const f4*)src)[0], v1 = ((const f4*)src)[1];
          h0.x = bf16t(v0.x); h0.y = bf16t(v0.y); h0.z = bf16t(v0.z); h0.w = bf16t(v0.w);
          h1.x = bf16t(v1.x); h1.y = bf16t(v1.y); h1.z = bf16t(v1.z); h1.w = bf16t(v1.w);
        }
        char* dst = wb + (size_t)((c * 8 + ks) * 8 + kf) * 1024 +
                    (lg * 16 + lm) * 16;
        *(short4v*)dst = h0;
        *(short4v*)(dst + 8) = h1;
      }
    }
  }
}

// ---------------- main kernel ----------------

__global__ __launch_bounds__(512, 1)
void rbf_main(const float* __restrict__ x, const char* __restrict__ cb2,
              const float* __restrict__ csqp, const char* __restrict__ wb2,
              const float* __restrict__ bvec, const float* __restrict__ gamma_p,
              float* __restrict__ out) {
  __shared__ alignas(16) char a_lds[64 * A_PITCH];        // 33792 B, x fp8
  __shared__ alignas(16) short phi_lds[2][64 * P_PITCH];  // 67584 B, phi dbuf
  __shared__ float xsq[64];

  const int tid = threadIdx.x;
  const int lane = tid & 63;
  const int wv = tid >> 6;   // 0..7
  const int h = wv >> 2;     // G1 row half
  const int g = wv & 3;      // G1 col group (frags g+4t)
  const int lm = lane & 15;
  const int lg = lane >> 4;
  const int m0 = blockIdx.x * 64;
  const float gma = gamma_p[0];
  const int laneoff = lane << 4;

  // ---- prologue: stage x tile (fp32->fp8 fragment-paired) + xsq ----
  {
    const int row = tid >> 3;   // 0..63
    const int seg = tid & 7;    // k block of 64
    const f4* xr = (const f4*)(x + (size_t)(m0 + row) * NF + seg * 64);
    float f[64];
    float ss = 0.f;
#pragma unroll
    for (int i = 0; i < 16; ++i) {
      f4 v = xr[i];
      f[4 * i] = v.x; f[4 * i + 1] = v.y; f[4 * i + 2] = v.z; f[4 * i + 3] = v.w;
      ss += v.x * v.x + v.y * v.y + v.z * v.z + v.w * v.w;
    }
    uint w[16];
#pragma unroll
    for (int m = 0; m < 16; ++m)
      w[m] = pk4_fp8(f[4 * m], f[4 * m + 1], f[4 * m + 2], f[4 * m + 3]);
    char* ar = a_lds + row * A_PITCH + seg * 64;
#pragma unroll
    for (int l2 = 0; l2 < 4; ++l2) {
      uint4v u = {w[2 * l2], w[2 * l2 + 1], w[8 + 2 * l2], w[9 + 2 * l2]};
      *(uint4v*)(ar + l2 * 16) = u;
    }
    ((float*)phi_lds[0])[tid] = ss;  // scratch partials (consumed pre-E0)
  }

  // B frag ring; preload chunk-0 stages 0,1 (drain at the prologue barriers)
  ulong2v bp[3][4];
#pragma unroll
  for (int t = 0; t < 4; ++t) {
    bp[0][t] = *(const ulong2v*)(cb2 + ((g + 4 * t) << 10) + laneoff);
    bp[1][t] = *(const ulong2v*)(cb2 + ((16 + g + 4 * t) << 10) + laneoff);
  }

  __syncthreads();  // publishes a_lds + partials
  if (tid < 64) {
    const float* pp = (const float*)phi_lds[0] + 8 * tid;
    xsq[tid] = pp[0] + pp[1] + pp[2] + pp[3] + pp[4] + pp[5] + pp[6] + pp[7];
  }
  __syncthreads();  // publishes xsq

  const f4 fzero = {0.f, 0.f, 0.f, 0.f};
  f4 acc2[4];
#pragma unroll
  for (int i = 0; i < 4; ++i) acc2[i] = fzero;

  for (int c = 0; c < 4; ++c) {
    float csr[4];
#pragma unroll
    for (int t = 0; t < 4; ++t)
      csr[t] = csqp[c * 256 + 16 * (g + 4 * t) + lm];

    f4 acc1[2][4];
#pragma unroll
    for (int i = 0; i < 2; ++i)
#pragma unroll
      for (int t = 0; t < 4; ++t) acc1[i][t] = fzero;

    // ---- GEMM1: 8 k=64 stages, no barriers, B ring-3 (distance 2) ----
    const char* bb = cb2 + (size_t)c * 131072;
#pragma unroll
    for (int kb = 0; kb < 8; ++kb) {
      if (kb < 6) {
#pragma unroll
        for (int t = 0; t < 4; ++t)
          bp[(kb + 2) % 3][t] = *(const ulong2v*)(
              bb + (((kb + 2) * 16 + g + 4 * t) << 10) + laneoff);
      }
      ulong2v a2[2];
#pragma unroll
      for (int i = 0; i < 2; ++i)
        a2[i] = *(const ulong2v*)(a_lds + (32 * h + 16 * i + lm) * A_PITCH +
                                  kb * 64 + lg * 16);
      const int cur = kb % 3;
#pragma unroll
      for (int i = 0; i < 2; ++i)
#pragma unroll
        for (int t = 0; t < 4; ++t)
          acc1[i][t] = __builtin_amdgcn_mfma_f32_16x16x32_fp8_fp8(
              (long)a2[i].x, (long)bp[cur][t].x, acc1[i][t], 0, 0, 0);
#pragma unroll
      for (int i = 0; i < 2; ++i)
#pragma unroll
        for (int t = 0; t < 4; ++t)
          acc1[i][t] = __builtin_amdgcn_mfma_f32_16x16x32_fp8_fp8(
              (long)a2[i].y, (long)bp[cur][t].y, acc1[i][t], 0, 0, 0);
    }

    // ---- preloads (in flight across epilogue; drained by the barrier) ----
    const char* wwb = wb2 + (size_t)c * 65536;
    short8 wp[8];   // wave owns kout frag wv for all 8 ks
#pragma unroll
    for (int ks = 0; ks < 8; ++ks)
      wp[ks] = *(const short8*)(wwb + ((ks * 8 + wv) << 10) + laneoff);
    if (c < 3) {
      const char* bbn = cb2 + (size_t)(c + 1) * 131072;
#pragma unroll
      for (int t = 0; t < 4; ++t) {
        bp[0][t] = *(const ulong2v*)(bbn + ((g + 4 * t) << 10) + laneoff);
        bp[1][t] = *(const ulong2v*)(bbn + ((16 + g + 4 * t) << 10) + laneoff);
      }
    }

    // ---- epilogue: phi = exp(-gamma*dist) -> phi_lds[c&1] (A layout) ----
    short* phb = phi_lds[c & 1];
#pragma unroll
    for (int t = 0; t < 4; ++t) {
      const float cs = csr[t];
      const int colh = 16 * (g + 4 * t) + lm;
#pragma unroll
      for (int i = 0; i < 2; ++i) {
#pragma unroll
        for (int r = 0; r < 4; ++r) {
          const int rowL = 32 * h + 16 * i + 4 * lg + r;
          float d2 = xsq[rowL] + cs - 2.0f * acc1[i][t][r];
          d2 = fmaxf(d2, 0.f);
          const float ph = __expf(-gma * __builtin_amdgcn_sqrtf(d2));
          phb[rowL * P_PITCH + colh] = bf16t(ph);
        }
      }
    }
    __syncthreads();  // the chunk's ONLY barrier: publishes phi, drains loads

    // ---- GEMM2: 8 k=32 steps, zero global stalls (W preloaded) ----
#pragma unroll
    for (int ks = 0; ks < 8; ++ks) {
      short8 pv[4];
#pragma unroll
      for (int i = 0; i < 4; ++i)
        pv[i] = *(const short8*)(phb + (16 * i + lm) * P_PITCH + ks * 32 +
                                 lg * 8);
#pragma unroll
      for (int i = 0; i < 4; ++i)
        acc2[i] = __builtin_amdgcn_mfma_f32_16x16x32_bf16(pv[i], wp[ks],
                                                          acc2[i], 0, 0, 0);
    }
  }

  // ---- out = acc2 + b, kout = 16*wv + lm < 100 ----
  const int kout = 16 * wv + lm;
  if (kout < NK) {
    const float bb2 = bvec[kout];
#pragma unroll
    for (int i = 0; i < 4; ++i) {
#pragma unroll
      for (int r = 0; r < 4; ++r) {
        const int row = m0 + 16 * i + 4 * lg + r;
        out[(size_t)row * NK + kout] = acc2[i][r] + bb2;
      }
    }
  }
}

// ---------------- fallback (round-1 kernel, used if ws too small) ----------------

#define A_PITCH1 520
#define BW_PITCH1 72
#define PHI_PITCH1 264

__global__ __launch_bounds__(256, 1)
void rbf_fused_v1(const float* __restrict__ x, const float* __restrict__ ctr,
                  const float* __restrict__ gamma_p, const float* __restrict__ W,
                  const float* __restrict__ bvec, float* __restrict__ out) {
  __shared__ alignas(16) short a_lds[64 * A_PITCH1];
  __shared__ alignas(16) short bw_lds[256 * BW_PITCH1];
  __shared__ alignas(16) short phi_lds[64 * PHI_PITCH1];
  __shared__ float xsq[64];
  __shared__ float csq[256];

  const int tid = threadIdx.x;
  const int lane = tid & 63;
  const int wv = tid >> 6;
  const int lm = lane & 15;
  const int lg = lane >> 4;
  const int m0 = blockIdx.x * 64;
  const float gma = gamma_p[0];

  {
    const int row = tid >> 2;
    const int seg = tid & 3;
    const float* xr = x + (size_t)(m0 + row) * NF + seg * 128;
    short* ar = a_lds + row * A_PITCH1 + seg * 128;
    float xp = 0.f;
#pragma unroll
    for (int i = 0; i < 32; ++i) {
      f4 v = ((const f4*)xr)[i];
      xp += v.x * v.x + v.y * v.y + v.z * v.z + v.w * v.w;
      short4v h;
      h.x = bf16t(v.x); h.y = bf16t(v.y); h.z = bf16t(v.z); h.w = bf16t(v.w);
      *(short4v*)(ar + i * 4) = h;
    }
    ((float*)phi_lds)[tid] = xp;
  }
  __syncthreads();
  if (tid < 64) {
    const float* pp = (const float*)phi_lds;
    xsq[tid] = pp[tid * 4] + pp[tid * 4 + 1] + pp[tid * 4 + 2] + pp[tid * 4 + 3];
  }

  const f4 fzero = {0.f, 0.f, 0.f, 0.f};
  f4 acc2[4][2];
#pragma unroll
  for (int i = 0; i < 4; ++i)
#pragma unroll
    for (int n = 0; n < 2; ++n) acc2[i][n] = fzero;

  const short* a_base = a_lds + lm * A_PITCH1 + lg * 8;
  const short* b_base = bw_lds + (64 * wv + lm) * BW_PITCH1 + lg * 8;
  const short* w_base = bw_lds + lm * BW_PITCH1 + lg * 8;
  const short* p_base = phi_lds + lm * PHI_PITCH1 + lg * 8;

  for (int chunk = 0; chunk < 4; ++chunk) {
    const int c0 = chunk * 256;
    f4 acc1[4][4];
#pragma unroll
    for (int i = 0; i < 4; ++i)
#pragma unroll
      for (int t = 0; t < 4; ++t) acc1[i][t] = fzero;
    float cpriv = 0.f;

    for (int kb = 0; kb < 8; ++kb) {
      __syncthreads();
      {
        const float* cr = ctr + (size_t)(c0 + tid) * NF + kb * 64;
        short* br = bw_lds + tid * BW_PITCH1;
#pragma unroll
        for (int i = 0; i < 16; ++i) {
          f4 v = ((const f4*)cr)[i];
          cpriv += v.x * v.x + v.y * v.y + v.z * v.z + v.w * v.w;
          short4v h;
          h.x = bf16t(v.x); h.y = bf16t(v.y); h.z = bf16t(v.z); h.w = bf16t(v.w);
          *(short4v*)(br + i * 4) = h;
        }
      }
      __syncthreads();
#pragma unroll
      for (int s = 0; s < 2; ++s) {
        short8 av[4], bv8[4];
#pragma unroll
        for (int i = 0; i < 4; ++i)
          av[i] = *(const short8*)(a_base + 16 * i * A_PITCH1 + 64 * kb + 32 * s);
#pragma unroll
        for (int t = 0; t < 4; ++t)
          bv8[t] = *(const short8*)(b_base + 16 * t * BW_PITCH1 + 32 * s);
#pragma unroll
        for (int i = 0; i < 4; ++i)
#pragma unroll
          for (int t = 0; t < 4; ++t)
            acc1[i][t] = __builtin_amdgcn_mfma_f32_16x16x32_bf16(
                av[i], bv8[t], acc1[i][t], 0, 0, 0);
      }
    }

    csq[tid] = cpriv;
    __syncthreads();

#pragma unroll
    for (int i = 0; i < 4; ++i) {
#pragma unroll
      for (int t = 0; t < 4; ++t) {
        const int colL = 64 * wv + 16 * t + lm;
        const float cs = csq[colL];
#pragma unroll
        for (int r = 0; r < 4; ++r) {
          const int rowL = 16 * i + 4 * lg + r;
          float d2 = xsq[rowL] + cs - 2.0f * acc1[i][t][r];
          d2 = fmaxf(d2, 0.f);
          const float ph = __expf(-gma * __fsqrt_rn(d2));
          phi_lds[rowL * PHI_PITCH1 + colL] = bf16t(ph);
        }
      }
    }

    for (int u = 0; u < 4; ++u) {
      __syncthreads();
      {
        const int row = tid >> 1;
        const int half = tid & 1;
        short* wr = bw_lds + row * BW_PITCH1 + half * 32;
        if (row < NK) {
          const float* ws = W + (size_t)row * NC + c0 + u * 64 + half * 32;
#pragma unroll
          for (int i = 0; i < 8; ++i) {
            f4 v = ((const f4*)ws)[i];
            short4v h;
            h.x = bf16t(v.x); h.y = bf16t(v.y); h.z = bf16t(v.z); h.w = bf16t(v.w);
            *(short4v*)(wr + i * 4) = h;
          }
        } else {
          const short4v zz = {0, 0, 0, 0};
#pragma unroll
          for (int i = 0; i < 8; ++i) *(short4v*)(wr + i * 4) = zz;
        }
      }
      __syncthreads();
#pragma unroll
      for (int s = 0; s < 2; ++s) {
        short8 pv[4], wv8[2];
#pragma unroll
        for (int i = 0; i < 4; ++i)
          pv[i] = *(const short8*)(p_base + 16 * i * PHI_PITCH1 + 64 * u + 32 * s);
#pragma unroll
        for (int n = 0; n < 2; ++n)
          wv8[n] = *(const short8*)(w_base + 16 * (2 * wv + n) * BW_PITCH1 + 32 * s);
#pragma unroll
        for (int i = 0; i < 4; ++i)
#pragma unroll
          for (int n = 0; n < 2; ++n)
            acc2[i][n] = __builtin_amdgcn_mfma_f32_16x16x32_bf16(
                pv[i], wv8[n], acc2[i][n], 0, 0, 0);
      }
    }
  }

#pragma unroll
  for (int i = 0; i < 4; ++i) {
#pragma unroll
    for (int n = 0; n < 2; ++n) {
      const int kout = 32 * wv + 16 * n + lm;
      if (kout < NK) {
        const float bb = bvec[kout];
#pragma unroll
        for (int r = 0; r < 4; ++r) {
          const int row = m0 + 16 * i + 4 * lg + r;
          out[(size_t)row * NK + kout] = acc2[i][n][r] + bb;
        }
      }
    }
  }
}

extern "C" void kernel_launch(void* const* d_in, const int* in_sizes, int n_in,
                              void* d_out, int out_size, void* d_ws, size_t ws_size,
                              hipStream_t stream) {
  (void)in_sizes; (void)n_in; (void)out_size;
  const float* x       = (const float*)d_in[0];
  const float* centers = (const float*)d_in[1];
  const float* gamma   = (const float*)d_in[2];
  const float* W       = (const float*)d_in[3];
  const float* b       = (const float*)d_in[4];
  float* out = (float*)d_out;

  if (ws_size >= (size_t)WS_NEED) {
    char* wsb = (char*)d_ws;
    char*  cbp  = wsb;                                  // 512KB fp8 centers
    float* csqp = (float*)(wsb + CB_BYTES);             // 1024 f32
    char*  wbp  = wsb + CB_BYTES + NC * 4;              // 256KB bf16 W
    prep_all<<<dim3(34), dim3(256), 0, stream>>>(centers, W, cbp, csqp, wbp);
    rbf_main<<<dim3(NB / 64), dim3(512), 0, stream>>>(x, cbp, csqp, wbp, b,
                                                      gamma, out);
  } else {
    rbf_fused_v1<<<dim3(NB / 64), dim3(256), 0, stream>>>(x, centers, gamma, W,
                                                          b, out);
  }
}

// Round 9
// 113.530 us; speedup vs baseline: 1.0283x; 1.0283x over previous
//
#include <hip/hip_runtime.h>

// RBFNN fused, round 9: revert to R7 (M=32, 2 blocks/CU) + smooth W burst.
// out[B,K] = exp(-gamma * dist(x, centers)) @ W^T + b
// B=16384, F=512, C=1024, K=100.
//
// R8 post-mortem: M=64 / 1 block/CU regressed (+4us). Per-CU L2 request
// rate is unchanged by M; what M=64 removed was the time-skewed second
// block's latency cover (decisive in R4/R5/R8). Reverted to R7 structure.
// One change vs R7: the 16 W-frag + 8 B-frag chunk-end preload burst
// (~128KB/CU in ~2.1k cyc, covered by only ~500 cyc of epilogue) is spread
// across the 8 G1 stages (2 W frags/stage) -> per-stage supply 32->40KB,
// no chunk-end burst, barrier drains shrink. Everything else = R7:
// fragment-ordered cb2 (fp8) / wb2 (bf16) in d_ws, barrier-free G1 with
// ring-3 B prefetch (distance 2), phi double-buffer, ONE barrier per chunk.

#define NB 16384
#define NF 512
#define NC 1024
#define NK 100

#define A_PITCH 528   // bytes/row (512 fp8 + 16 pad)
#define P_PITCH 264   // shorts/row (256 bf16 + 8 pad)

#define CB_BYTES (NC * NF)      // 512KB fp8 centers, fragment-ordered
#define WB_BYTES (256 * 1024)   // 256KB bf16 W (100->128 kouts), frag-ordered
#define WS_NEED (CB_BYTES + NC * 4 + WB_BYTES)

typedef __attribute__((ext_vector_type(8))) short short8;
typedef __attribute__((ext_vector_type(4))) short short4v;
typedef __attribute__((ext_vector_type(4))) float f4;
typedef __attribute__((ext_vector_type(4))) unsigned int uint4v;
typedef __attribute__((ext_vector_type(2))) unsigned long ulong2v;
typedef unsigned short ushort;
typedef unsigned int uint;

__device__ __forceinline__ short bf16t(float f) {
  return (short)(__float_as_uint(f) >> 16);
}

__device__ __forceinline__ uint pk4_fp8(float a, float b, float c, float d) {
  uint r = __builtin_amdgcn_cvt_pk_fp8_f32(a, b, 0, false);
  return __builtin_amdgcn_cvt_pk_fp8_f32(c, d, r, true);
}

// ---------------- merged prepass (layouts unchanged since R6) ----------------
__global__ __launch_bounds__(256) void prep_all(
    const float* __restrict__ ctr, const float* __restrict__ W,
    char* __restrict__ cb, float* __restrict__ csq, char* __restrict__ wb) {
  if (blockIdx.x < 32) {
    const int t = blockIdx.x * 256 + threadIdx.x;  // 0..8191
    const int cg = t >> 3;                          // center row 0..1023
    const int kb = t & 7;
    const f4* src = (const f4*)(ctr + (size_t)cg * NF + kb * 64);
    float f[64];
    float ss = 0.f;
#pragma unroll
    for (int i = 0; i < 16; ++i) {
      f4 v = src[i];
      f[4 * i] = v.x; f[4 * i + 1] = v.y; f[4 * i + 2] = v.z; f[4 * i + 3] = v.w;
      ss += v.x * v.x + v.y * v.y + v.z * v.z + v.w * v.w;
    }
    uint w[16];
#pragma unroll
    for (int m = 0; m < 16; ++m)
      w[m] = pk4_fp8(f[4 * m], f[4 * m + 1], f[4 * m + 2], f[4 * m + 3]);
    const int c = cg >> 8, fr = (cg >> 4) & 15, lm = cg & 15;
    char* base = cb + (size_t)((c * 8 + kb) * 16 + fr) * 1024 + lm * 16;
#pragma unroll
    for (int lg = 0; lg < 4; ++lg) {
      uint4v u = {w[2 * lg], w[2 * lg + 1], w[8 + 2 * lg], w[9 + 2 * lg]};
      *(uint4v*)(base + lg * 256) = u;
    }
    ss += __shfl_down(ss, 4, 64);
    ss += __shfl_down(ss, 2, 64);
    ss += __shfl_down(ss, 1, 64);
    if (kb == 0) csq[cg] = ss;
  } else {
    const int t = (blockIdx.x - 32) * 256 + threadIdx.x;  // 0..511
    const int kout = t >> 2, c = t & 3;
    const int kf = kout >> 4, lm = kout & 15;
#pragma unroll
    for (int ks = 0; ks < 8; ++ks) {
#pragma unroll
      for (int lg = 0; lg < 4; ++lg) {
        short4v h0 = {0, 0, 0, 0}, h1 = {0, 0, 0, 0};
        if (kout < NK) {
          const float* src = W + (size_t)kout * NC + c * 256 + ks * 32 + lg * 8;
          f4 v0 = ((const f4*)src)[0], v1 = ((const f4*)src)[1];
          h0.x = bf16t(v0.x); h0.y = bf16t(v0.y); h0.z = bf16t(v0.z); h0.w = bf16t(v0.w);
          h1.x = bf16t(v1.x); h1.y = bf16t(v1.y); h1.z = bf16t(v1.z); h1.w = bf16t(v1.w);
        }
        char* dst = wb + (size_t)((c * 8 + ks) * 8 + kf) * 1024 +
                    (lg * 16 + lm) * 16;
        *(short4v*)dst = h0;
        *(short4v*)(dst + 8) = h1;
      }
    }
  }
}

// ---------------- main kernel ----------------

__global__ __launch_bounds__(256, 2)
void rbf_main(const float* __restrict__ x, const char* __restrict__ cb2,
              const float* __restrict__ csqp, const char* __restrict__ wb2,
              const float* __restrict__ bvec, const float* __restrict__ gamma_p,
              float* __restrict__ out) {
  __shared__ alignas(16) char a_lds[32 * A_PITCH];        // 16896 B, x fp8
  __shared__ alignas(16) short phi_lds[2][32 * P_PITCH];  // 33792 B, phi dbuf
  __shared__ float xsq[32];

  const int tid = threadIdx.x;
  const int lane = tid & 63;
  const int wv = tid >> 6;   // 0..3
  const int lm = lane & 15;
  const int lg = lane >> 4;
  const int m0 = blockIdx.x * 32;
  const float gma = gamma_p[0];
  const int laneoff = lane << 4;

  // ---- prologue: stage x tile (fp32->fp8 fragment-paired) + xsq ----
  {
    const int row = tid >> 3;   // 0..31
    const int seg = tid & 7;    // k block of 64
    const f4* xr = (const f4*)(x + (size_t)(m0 + row) * NF + seg * 64);
    float f[64];
    float ss = 0.f;
#pragma unroll
    for (int i = 0; i < 16; ++i) {
      f4 v = xr[i];
      f[4 * i] = v.x; f[4 * i + 1] = v.y; f[4 * i + 2] = v.z; f[4 * i + 3] = v.w;
      ss += v.x * v.x + v.y * v.y + v.z * v.z + v.w * v.w;
    }
    uint w[16];
#pragma unroll
    for (int m = 0; m < 16; ++m)
      w[m] = pk4_fp8(f[4 * m], f[4 * m + 1], f[4 * m + 2], f[4 * m + 3]);
    char* ar = a_lds + row * A_PITCH + seg * 64;
#pragma unroll
    for (int l2 = 0; l2 < 4; ++l2) {
      uint4v u = {w[2 * l2], w[2 * l2 + 1], w[8 + 2 * l2], w[9 + 2 * l2]};
      *(uint4v*)(ar + l2 * 16) = u;
    }
    ((float*)phi_lds[0])[tid] = ss;  // scratch partials (consumed pre-E0)
  }

  // B frag ring; preload chunk-0 stages 0,1 (drain at the prologue barriers)
  ulong2v bp[3][4];
#pragma unroll
  for (int t = 0; t < 4; ++t) {
    bp[0][t] = *(const ulong2v*)(cb2 + ((wv + 4 * t) << 10) + laneoff);
    bp[1][t] = *(const ulong2v*)(cb2 + ((16 + wv + 4 * t) << 10) + laneoff);
  }

  __syncthreads();  // publishes a_lds + partials
  if (tid < 32) {
    const float* pp = (const float*)phi_lds[0] + 8 * tid;
    xsq[tid] = pp[0] + pp[1] + pp[2] + pp[3] + pp[4] + pp[5] + pp[6] + pp[7];
  }
  __syncthreads();  // publishes xsq

  const f4 fzero = {0.f, 0.f, 0.f, 0.f};
  f4 acc2[2][2];
#pragma unroll
  for (int i = 0; i < 2; ++i)
#pragma unroll
    for (int n = 0; n < 2; ++n) acc2[i][n] = fzero;

  for (int c = 0; c < 4; ++c) {
    float csr[4];
#pragma unroll
    for (int t = 0; t < 4; ++t)
      csr[t] = csqp[c * 256 + 16 * (wv + 4 * t) + lm];

    f4 acc1[2][4];
#pragma unroll
    for (int i = 0; i < 2; ++i)
#pragma unroll
      for (int t = 0; t < 4; ++t) acc1[i][t] = fzero;

    // ---- GEMM1: 8 k=64 stages, no barriers, B ring-3 (distance 2),
    //      W stage-pair ks=kb loaded at stage kb (burst spread) ----
    const char* bb = cb2 + (size_t)c * 131072;
    const char* wwb = wb2 + (size_t)c * 65536;
    short8 wp[8][2];
#pragma unroll
    for (int kb = 0; kb < 8; ++kb) {
      if (kb < 6) {
#pragma unroll
        for (int t = 0; t < 4; ++t)
          bp[(kb + 2) % 3][t] = *(const ulong2v*)(
              bb + (((kb + 2) * 16 + wv + 4 * t) << 10) + laneoff);
      }
#pragma unroll
      for (int n = 0; n < 2; ++n)
        wp[kb][n] = *(const short8*)(wwb + ((kb * 8 + 2 * wv + n) << 10) +
                                     laneoff);
      ulong2v a2[2];
#pragma unroll
      for (int i = 0; i < 2; ++i)
        a2[i] = *(const ulong2v*)(a_lds + (16 * i + lm) * A_PITCH + kb * 64 +
                                  lg * 16);
      const int cur = kb % 3;
#pragma unroll
      for (int i = 0; i < 2; ++i)
#pragma unroll
        for (int t = 0; t < 4; ++t)
          acc1[i][t] = __builtin_amdgcn_mfma_f32_16x16x32_fp8_fp8(
              (long)a2[i].x, (long)bp[cur][t].x, acc1[i][t], 0, 0, 0);
#pragma unroll
      for (int i = 0; i < 2; ++i)
#pragma unroll
        for (int t = 0; t < 4; ++t)
          acc1[i][t] = __builtin_amdgcn_mfma_f32_16x16x32_fp8_fp8(
              (long)a2[i].y, (long)bp[cur][t].y, acc1[i][t], 0, 0, 0);
    }

    // ---- next-chunk B preload (in flight across epilogue + barrier) ----
    if (c < 3) {
      const char* bbn = cb2 + (size_t)(c + 1) * 131072;
#pragma unroll
      for (int t = 0; t < 4; ++t) {
        bp[0][t] = *(const ulong2v*)(bbn + ((wv + 4 * t) << 10) + laneoff);
        bp[1][t] = *(const ulong2v*)(bbn + ((16 + wv + 4 * t) << 10) + laneoff);
      }
    }

    // ---- epilogue: phi = exp(-gamma*dist) -> phi_lds[c&1] (A layout) ----
    short* phb = phi_lds[c & 1];
#pragma unroll
    for (int t = 0; t < 4; ++t) {
      const float cs = csr[t];
      const int colh = 16 * (wv + 4 * t) + lm;
#pragma unroll
      for (int i = 0; i < 2; ++i) {
#pragma unroll
        for (int r = 0; r < 4; ++r) {
          const int rowL = 16 * i + 4 * lg + r;
          float d2 = xsq[rowL] + cs - 2.0f * acc1[i][t][r];
          d2 = fmaxf(d2, 0.f);
          const float ph = __expf(-gma * __builtin_amdgcn_sqrtf(d2));
          phb[rowL * P_PITCH + colh] = bf16t(ph);
        }
      }
    }
    __syncthreads();  // the chunk's ONLY barrier: publishes phi, drains loads

    // ---- GEMM2: 8 k=32 steps, zero global stalls (W preloaded) ----
#pragma unroll
    for (int ks = 0; ks < 8; ++ks) {
      short8 pv[2];
#pragma unroll
      for (int i = 0; i < 2; ++i)
        pv[i] = *(const short8*)(phb + (16 * i + lm) * P_PITCH + ks * 32 +
                                 lg * 8);
#pragma unroll
      for (int i = 0; i < 2; ++i)
#pragma unroll
        for (int n = 0; n < 2; ++n)
          acc2[i][n] = __builtin_amdgcn_mfma_f32_16x16x32_bf16(
              pv[i], wp[ks][n], acc2[i][n], 0, 0, 0);
    }
  }

  // ---- out = acc2 + b, kout = 32wv + 16n + lm < 100 ----
#pragma unroll
  for (int i = 0; i < 2; ++i) {
#pragma unroll
    for (int n = 0; n < 2; ++n) {
      const int kout = 32 * wv + 16 * n + lm;
      if (kout < NK) {
        const float bb2 = bvec[kout];
#pragma unroll
        for (int r = 0; r < 4; ++r) {
          const int row = m0 + 16 * i + 4 * lg + r;
          out[(size_t)row * NK + kout] = acc2[i][n][r] + bb2;
        }
      }
    }
  }
}

// ---------------- fallback (round-1 kernel, used if ws too small) ----------------

#define A_PITCH1 520
#define BW_PITCH1 72
#define PHI_PITCH1 264

__global__ __launch_bounds__(256, 1)
void rbf_fused_v1(const float* __restrict__ x, const float* __restrict__ ctr,
                  const float* __restrict__ gamma_p, const float* __restrict__ W,
                  const float* __restrict__ bvec, float* __restrict__ out) {
  __shared__ alignas(16) short a_lds[64 * A_PITCH1];
  __shared__ alignas(16) short bw_lds[256 * BW_PITCH1];
  __shared__ alignas(16) short phi_lds[64 * PHI_PITCH1];
  __shared__ float xsq[64];
  __shared__ float csq[256];

  const int tid = threadIdx.x;
  const int lane = tid & 63;
  const int wv = tid >> 6;
  const int lm = lane & 15;
  const int lg = lane >> 4;
  const int m0 = blockIdx.x * 64;
  const float gma = gamma_p[0];

  {
    const int row = tid >> 2;
    const int seg = tid & 3;
    const float* xr = x + (size_t)(m0 + row) * NF + seg * 128;
    short* ar = a_lds + row * A_PITCH1 + seg * 128;
    float xp = 0.f;
#pragma unroll
    for (int i = 0; i < 32; ++i) {
      f4 v = ((const f4*)xr)[i];
      xp += v.x * v.x + v.y * v.y + v.z * v.z + v.w * v.w;
      short4v h;
      h.x = bf16t(v.x); h.y = bf16t(v.y); h.z = bf16t(v.z); h.w = bf16t(v.w);
      *(short4v*)(ar + i * 4) = h;
    }
    ((float*)phi_lds)[tid] = xp;
  }
  __syncthreads();
  if (tid < 64) {
    const float* pp = (const float*)phi_lds;
    xsq[tid] = pp[tid * 4] + pp[tid * 4 + 1] + pp[tid * 4 + 2] + pp[tid * 4 + 3];
  }

  const f4 fzero = {0.f, 0.f, 0.f, 0.f};
  f4 acc2[4][2];
#pragma unroll
  for (int i = 0; i < 4; ++i)
#pragma unroll
    for (int n = 0; n < 2; ++n) acc2[i][n] = fzero;

  const short* a_base = a_lds + lm * A_PITCH1 + lg * 8;
  const short* b_base = bw_lds + (64 * wv + lm) * BW_PITCH1 + lg * 8;
  const short* w_base = bw_lds + lm * BW_PITCH1 + lg * 8;
  const short* p_base = phi_lds + lm * PHI_PITCH1 + lg * 8;

  for (int chunk = 0; chunk < 4; ++chunk) {
    const int c0 = chunk * 256;
    f4 acc1[4][4];
#pragma unroll
    for (int i = 0; i < 4; ++i)
#pragma unroll
      for (int t = 0; t < 4; ++t) acc1[i][t] = fzero;
    float cpriv = 0.f;

    for (int kb = 0; kb < 8; ++kb) {
      __syncthreads();
      {
        const float* cr = ctr + (size_t)(c0 + tid) * NF + kb * 64;
        short* br = bw_lds + tid * BW_PITCH1;
#pragma unroll
        for (int i = 0; i < 16; ++i) {
          f4 v = ((const f4*)cr)[i];
          cpriv += v.x * v.x + v.y * v.y + v.z * v.z + v.w * v.w;
          short4v h;
          h.x = bf16t(v.x); h.y = bf16t(v.y); h.z = bf16t(v.z); h.w = bf16t(v.w);
          *(short4v*)(br + i * 4) = h;
        }
      }
      __syncthreads();
#pragma unroll
      for (int s = 0; s < 2; ++s) {
        short8 av[4], bv8[4];
#pragma unroll
        for (int i = 0; i < 4; ++i)
          av[i] = *(const short8*)(a_base + 16 * i * A_PITCH1 + 64 * kb + 32 * s);
#pragma unroll
        for (int t = 0; t < 4; ++t)
          bv8[t] = *(const short8*)(b_base + 16 * t * BW_PITCH1 + 32 * s);
#pragma unroll
        for (int i = 0; i < 4; ++i)
#pragma unroll
          for (int t = 0; t < 4; ++t)
            acc1[i][t] = __builtin_amdgcn_mfma_f32_16x16x32_bf16(
                av[i], bv8[t], acc1[i][t], 0, 0, 0);
      }
    }

    csq[tid] = cpriv;
    __syncthreads();

#pragma unroll
    for (int i = 0; i < 4; ++i) {
#pragma unroll
      for (int t = 0; t < 4; ++t) {
        const int colL = 64 * wv + 16 * t + lm;
        const float cs = csq[colL];
#pragma unroll
        for (int r = 0; r < 4; ++r) {
          const int rowL = 16 * i + 4 * lg + r;
          float d2 = xsq[rowL] + cs - 2.0f * acc1[i][t][r];
          d2 = fmaxf(d2, 0.f);
          const float ph = __expf(-gma * __fsqrt_rn(d2));
          phi_lds[rowL * PHI_PITCH1 + colL] = bf16t(ph);
        }
      }
    }

    for (int u = 0; u < 4; ++u) {
      __syncthreads();
      {
        const int row = tid >> 1;
        const int half = tid & 1;
        short* wr = bw_lds + row * BW_PITCH1 + half * 32;
        if (row < NK) {
          const float* ws = W + (size_t)row * NC + c0 + u * 64 + half * 32;
#pragma unroll
          for (int i = 0; i < 8; ++i) {
            f4 v = ((const f4*)ws)[i];
            short4v h;
            h.x = bf16t(v.x); h.y = bf16t(v.y); h.z = bf16t(v.z); h.w = bf16t(v.w);
            *(short4v*)(wr + i * 4) = h;
          }
        } else {
          const short4v zz = {0, 0, 0, 0};
#pragma unroll
          for (int i = 0; i < 8; ++i) *(short4v*)(wr + i * 4) = zz;
        }
      }
      __syncthreads();
#pragma unroll
      for (int s = 0; s < 2; ++s) {
        short8 pv[4], wv8[2];
#pragma unroll
        for (int i = 0; i < 4; ++i)
          pv[i] = *(const short8*)(p_base + 16 * i * PHI_PITCH1 + 64 * u + 32 * s);
#pragma unroll
        for (int n = 0; n < 2; ++n)
          wv8[n] = *(const short8*)(w_base + 16 * (2 * wv + n) * BW_PITCH1 + 32 * s);
#pragma unroll
        for (int i = 0; i < 4; ++i)
#pragma unroll
          for (int n = 0; n < 2; ++n)
            acc2[i][n] = __builtin_amdgcn_mfma_f32_16x16x32_bf16(
                pv[i], wv8[n], acc2[i][n], 0, 0, 0);
      }
    }
  }

#pragma unroll
  for (int i = 0; i < 4; ++i) {
#pragma unroll
    for (int n = 0; n < 2; ++n) {
      const int kout = 32 * wv + 16 * n + lm;
      if (kout < NK) {
        const float bb = bvec[kout];
#pragma unroll
        for (int r = 0; r < 4; ++r) {
          const int row = m0 + 16 * i + 4 * lg + r;
          out[(size_t)row * NK + kout] = acc2[i][n][r] + bb;
        }
      }
    }
  }
}

extern "C" void kernel_launch(void* const* d_in, const int* in_sizes, int n_in,
                              void* d_out, int out_size, void* d_ws, size_t ws_size,
                              hipStream_t stream) {
  (void)in_sizes; (void)n_in; (void)out_size;
  const float* x       = (const float*)d_in[0];
  const float* centers = (const float*)d_in[1];
  const float* gamma   = (const float*)d_in[2];
  const float* W       = (const float*)d_in[3];
  const float* b       = (const float*)d_in[4];
  float* out = (float*)d_out;

  if (ws_size >= (size_t)WS_NEED) {
    char* wsb = (char*)d_ws;
    char*  cbp  = wsb;                                  // 512KB fp8 centers
    float* csqp = (float*)(wsb + CB_BYTES);             // 1024 f32
    char*  wbp  = wsb + CB_BYTES + NC * 4;              // 256KB bf16 W
    prep_all<<<dim3(34), dim3(256), 0, stream>>>(centers, W, cbp, csqp, wbp);
    rbf_main<<<dim3(NB / 32), dim3(256), 0, stream>>>(x, cbp, csqp, wbp, b,
                                                      gamma, out);
  } else {
    rbf_fused_v1<<<dim3(NB / 64), dim3(256), 0, stream>>>(x, centers, gamma, W,
                                                          b, out);
  }
}

// Round 10
// 113.270 us; speedup vs baseline: 1.0307x; 1.0023x over previous
//
#include <hip/hip_runtime.h>

// RBFNN fused, round 10: R9 + B-ring depth 4 (prefetch distance 3).
// out[B,K] = exp(-gamma * dist(x, centers)) @ W^T + b
// B=16384, F=512, C=1024, K=100.
//
// R9 was a tie with R7 (~113 vs 112 us; W-burst spread neutral). Remaining
// G1 exposure: ring-3 B prefetch = 2-stage cover (~300-600 cyc) vs loaded
// L2 latency ~300-500 cyc -- marginal. This round: ring-4, distance 3
// (~450-900 cyc cover). Stage s issued at kb=s-3; slots 0,1,2 preloaded in
// the prologue / chunk-end shadow (drained free at the barrier). +16 VGPR
// (~186, still the 2-waves/SIMD band). Everything else identical to R9:
// fragment-ordered cb2 (fp8) / wb2 (bf16) in d_ws, barrier-free G1, W
// stage-pair loads spread across G1 stages, phi double-buffer, ONE barrier
// per chunk (6 total), M=32 blocks x 2/CU (the cover mechanism proven by
// R4/R5/R8).

#define NB 16384
#define NF 512
#define NC 1024
#define NK 100

#define A_PITCH 528   // bytes/row (512 fp8 + 16 pad)
#define P_PITCH 264   // shorts/row (256 bf16 + 8 pad)

#define CB_BYTES (NC * NF)      // 512KB fp8 centers, fragment-ordered
#define WB_BYTES (256 * 1024)   // 256KB bf16 W (100->128 kouts), frag-ordered
#define WS_NEED (CB_BYTES + NC * 4 + WB_BYTES)

typedef __attribute__((ext_vector_type(8))) short short8;
typedef __attribute__((ext_vector_type(4))) short short4v;
typedef __attribute__((ext_vector_type(4))) float f4;
typedef __attribute__((ext_vector_type(4))) unsigned int uint4v;
typedef __attribute__((ext_vector_type(2))) unsigned long ulong2v;
typedef unsigned short ushort;
typedef unsigned int uint;

__device__ __forceinline__ short bf16t(float f) {
  return (short)(__float_as_uint(f) >> 16);
}

__device__ __forceinline__ uint pk4_fp8(float a, float b, float c, float d) {
  uint r = __builtin_amdgcn_cvt_pk_fp8_f32(a, b, 0, false);
  return __builtin_amdgcn_cvt_pk_fp8_f32(c, d, r, true);
}

// ---------------- merged prepass (layouts unchanged since R6) ----------------
__global__ __launch_bounds__(256) void prep_all(
    const float* __restrict__ ctr, const float* __restrict__ W,
    char* __restrict__ cb, float* __restrict__ csq, char* __restrict__ wb) {
  if (blockIdx.x < 32) {
    const int t = blockIdx.x * 256 + threadIdx.x;  // 0..8191
    const int cg = t >> 3;                          // center row 0..1023
    const int kb = t & 7;
    const f4* src = (const f4*)(ctr + (size_t)cg * NF + kb * 64);
    float f[64];
    float ss = 0.f;
#pragma unroll
    for (int i = 0; i < 16; ++i) {
      f4 v = src[i];
      f[4 * i] = v.x; f[4 * i + 1] = v.y; f[4 * i + 2] = v.z; f[4 * i + 3] = v.w;
      ss += v.x * v.x + v.y * v.y + v.z * v.z + v.w * v.w;
    }
    uint w[16];
#pragma unroll
    for (int m = 0; m < 16; ++m)
      w[m] = pk4_fp8(f[4 * m], f[4 * m + 1], f[4 * m + 2], f[4 * m + 3]);
    const int c = cg >> 8, fr = (cg >> 4) & 15, lm = cg & 15;
    char* base = cb + (size_t)((c * 8 + kb) * 16 + fr) * 1024 + lm * 16;
#pragma unroll
    for (int lg = 0; lg < 4; ++lg) {
      uint4v u = {w[2 * lg], w[2 * lg + 1], w[8 + 2 * lg], w[9 + 2 * lg]};
      *(uint4v*)(base + lg * 256) = u;
    }
    ss += __shfl_down(ss, 4, 64);
    ss += __shfl_down(ss, 2, 64);
    ss += __shfl_down(ss, 1, 64);
    if (kb == 0) csq[cg] = ss;
  } else {
    const int t = (blockIdx.x - 32) * 256 + threadIdx.x;  // 0..511
    const int kout = t >> 2, c = t & 3;
    const int kf = kout >> 4, lm = kout & 15;
#pragma unroll
    for (int ks = 0; ks < 8; ++ks) {
#pragma unroll
      for (int lg = 0; lg < 4; ++lg) {
        short4v h0 = {0, 0, 0, 0}, h1 = {0, 0, 0, 0};
        if (kout < NK) {
          const float* src = W + (size_t)kout * NC + c * 256 + ks * 32 + lg * 8;
          f4 v0 = ((const f4*)src)[0], v1 = ((const f4*)src)[1];
          h0.x = bf16t(v0.x); h0.y = bf16t(v0.y); h0.z = bf16t(v0.z); h0.w = bf16t(v0.w);
          h1.x = bf16t(v1.x); h1.y = bf16t(v1.y); h1.z = bf16t(v1.z); h1.w = bf16t(v1.w);
        }
        char* dst = wb + (size_t)((c * 8 + ks) * 8 + kf) * 1024 +
                    (lg * 16 + lm) * 16;
        *(short4v*)dst = h0;
        *(short4v*)(dst + 8) = h1;
      }
    }
  }
}

// ---------------- main kernel ----------------

__global__ __launch_bounds__(256, 2)
void rbf_main(const float* __restrict__ x, const char* __restrict__ cb2,
              const float* __restrict__ csqp, const char* __restrict__ wb2,
              const float* __restrict__ bvec, const float* __restrict__ gamma_p,
              float* __restrict__ out) {
  __shared__ alignas(16) char a_lds[32 * A_PITCH];        // 16896 B, x fp8
  __shared__ alignas(16) short phi_lds[2][32 * P_PITCH];  // 33792 B, phi dbuf
  __shared__ float xsq[32];

  const int tid = threadIdx.x;
  const int lane = tid & 63;
  const int wv = tid >> 6;   // 0..3
  const int lm = lane & 15;
  const int lg = lane >> 4;
  const int m0 = blockIdx.x * 32;
  const float gma = gamma_p[0];
  const int laneoff = lane << 4;

  // ---- prologue: stage x tile (fp32->fp8 fragment-paired) + xsq ----
  {
    const int row = tid >> 3;   // 0..31
    const int seg = tid & 7;    // k block of 64
    const f4* xr = (const f4*)(x + (size_t)(m0 + row) * NF + seg * 64);
    float f[64];
    float ss = 0.f;
#pragma unroll
    for (int i = 0; i < 16; ++i) {
      f4 v = xr[i];
      f[4 * i] = v.x; f[4 * i + 1] = v.y; f[4 * i + 2] = v.z; f[4 * i + 3] = v.w;
      ss += v.x * v.x + v.y * v.y + v.z * v.z + v.w * v.w;
    }
    uint w[16];
#pragma unroll
    for (int m = 0; m < 16; ++m)
      w[m] = pk4_fp8(f[4 * m], f[4 * m + 1], f[4 * m + 2], f[4 * m + 3]);
    char* ar = a_lds + row * A_PITCH + seg * 64;
#pragma unroll
    for (int l2 = 0; l2 < 4; ++l2) {
      uint4v u = {w[2 * l2], w[2 * l2 + 1], w[8 + 2 * l2], w[9 + 2 * l2]};
      *(uint4v*)(ar + l2 * 16) = u;
    }
    ((float*)phi_lds[0])[tid] = ss;  // scratch partials (consumed pre-E0)
  }

  // B frag ring-4; preload chunk-0 stages 0,1,2 (drain at prologue barriers)
  ulong2v bp[4][4];
#pragma unroll
  for (int t = 0; t < 4; ++t) {
    bp[0][t] = *(const ulong2v*)(cb2 + ((wv + 4 * t) << 10) + laneoff);
    bp[1][t] = *(const ulong2v*)(cb2 + ((16 + wv + 4 * t) << 10) + laneoff);
    bp[2][t] = *(const ulong2v*)(cb2 + ((32 + wv + 4 * t) << 10) + laneoff);
  }

  __syncthreads();  // publishes a_lds + partials
  if (tid < 32) {
    const float* pp = (const float*)phi_lds[0] + 8 * tid;
    xsq[tid] = pp[0] + pp[1] + pp[2] + pp[3] + pp[4] + pp[5] + pp[6] + pp[7];
  }
  __syncthreads();  // publishes xsq

  const f4 fzero = {0.f, 0.f, 0.f, 0.f};
  f4 acc2[2][2];
#pragma unroll
  for (int i = 0; i < 2; ++i)
#pragma unroll
    for (int n = 0; n < 2; ++n) acc2[i][n] = fzero;

  for (int c = 0; c < 4; ++c) {
    float csr[4];
#pragma unroll
    for (int t = 0; t < 4; ++t)
      csr[t] = csqp[c * 256 + 16 * (wv + 4 * t) + lm];

    f4 acc1[2][4];
#pragma unroll
    for (int i = 0; i < 2; ++i)
#pragma unroll
      for (int t = 0; t < 4; ++t) acc1[i][t] = fzero;

    // ---- GEMM1: 8 k=64 stages, no barriers, B ring-4 (distance 3),
    //      W stage-pair ks=kb loaded at stage kb (burst spread) ----
    const char* bb = cb2 + (size_t)c * 131072;
    const char* wwb = wb2 + (size_t)c * 65536;
    short8 wp[8][2];
#pragma unroll
    for (int kb = 0; kb < 8; ++kb) {
      if (kb < 5) {
#pragma unroll
        for (int t = 0; t < 4; ++t)
          bp[(kb + 3) & 3][t] = *(const ulong2v*)(
              bb + (((kb + 3) * 16 + wv + 4 * t) << 10) + laneoff);
      }
#pragma unroll
      for (int n = 0; n < 2; ++n)
        wp[kb][n] = *(const short8*)(wwb + ((kb * 8 + 2 * wv + n) << 10) +
                                     laneoff);
      ulong2v a2[2];
#pragma unroll
      for (int i = 0; i < 2; ++i)
        a2[i] = *(const ulong2v*)(a_lds + (16 * i + lm) * A_PITCH + kb * 64 +
                                  lg * 16);
      const int cur = kb & 3;
#pragma unroll
      for (int i = 0; i < 2; ++i)
#pragma unroll
        for (int t = 0; t < 4; ++t)
          acc1[i][t] = __builtin_amdgcn_mfma_f32_16x16x32_fp8_fp8(
              (long)a2[i].x, (long)bp[cur][t].x, acc1[i][t], 0, 0, 0);
#pragma unroll
      for (int i = 0; i < 2; ++i)
#pragma unroll
        for (int t = 0; t < 4; ++t)
          acc1[i][t] = __builtin_amdgcn_mfma_f32_16x16x32_fp8_fp8(
              (long)a2[i].y, (long)bp[cur][t].y, acc1[i][t], 0, 0, 0);
    }

    // ---- next-chunk B preload: stages 0,1,2 (in flight across epilogue) ----
    if (c < 3) {
      const char* bbn = cb2 + (size_t)(c + 1) * 131072;
#pragma unroll
      for (int t = 0; t < 4; ++t) {
        bp[0][t] = *(const ulong2v*)(bbn + ((wv + 4 * t) << 10) + laneoff);
        bp[1][t] = *(const ulong2v*)(bbn + ((16 + wv + 4 * t) << 10) + laneoff);
        bp[2][t] = *(const ulong2v*)(bbn + ((32 + wv + 4 * t) << 10) + laneoff);
      }
    }

    // ---- epilogue: phi = exp(-gamma*dist) -> phi_lds[c&1] (A layout) ----
    short* phb = phi_lds[c & 1];
#pragma unroll
    for (int t = 0; t < 4; ++t) {
      const float cs = csr[t];
      const int colh = 16 * (wv + 4 * t) + lm;
#pragma unroll
      for (int i = 0; i < 2; ++i) {
#pragma unroll
        for (int r = 0; r < 4; ++r) {
          const int rowL = 16 * i + 4 * lg + r;
          float d2 = xsq[rowL] + cs - 2.0f * acc1[i][t][r];
          d2 = fmaxf(d2, 0.f);
          const float ph = __expf(-gma * __builtin_amdgcn_sqrtf(d2));
          phb[rowL * P_PITCH + colh] = bf16t(ph);
        }
      }
    }
    __syncthreads();  // the chunk's ONLY barrier: publishes phi, drains loads

    // ---- GEMM2: 8 k=32 steps, zero global stalls (W preloaded) ----
#pragma unroll
    for (int ks = 0; ks < 8; ++ks) {
      short8 pv[2];
#pragma unroll
      for (int i = 0; i < 2; ++i)
        pv[i] = *(const short8*)(phb + (16 * i + lm) * P_PITCH + ks * 32 +
                                 lg * 8);
#pragma unroll
      for (int i = 0; i < 2; ++i)
#pragma unroll
        for (int n = 0; n < 2; ++n)
          acc2[i][n] = __builtin_amdgcn_mfma_f32_16x16x32_bf16(
              pv[i], wp[ks][n], acc2[i][n], 0, 0, 0);
    }
  }

  // ---- out = acc2 + b, kout = 32wv + 16n + lm < 100 ----
#pragma unroll
  for (int i = 0; i < 2; ++i) {
#pragma unroll
    for (int n = 0; n < 2; ++n) {
      const int kout = 32 * wv + 16 * n + lm;
      if (kout < NK) {
        const float bb2 = bvec[kout];
#pragma unroll
        for (int r = 0; r < 4; ++r) {
          const int row = m0 + 16 * i + 4 * lg + r;
          out[(size_t)row * NK + kout] = acc2[i][n][r] + bb2;
        }
      }
    }
  }
}

// ---------------- fallback (round-1 kernel, used if ws too small) ----------------

#define A_PITCH1 520
#define BW_PITCH1 72
#define PHI_PITCH1 264

__global__ __launch_bounds__(256, 1)
void rbf_fused_v1(const float* __restrict__ x, const float* __restrict__ ctr,
                  const float* __restrict__ gamma_p, const float* __restrict__ W,
                  const float* __restrict__ bvec, float* __restrict__ out) {
  __shared__ alignas(16) short a_lds[64 * A_PITCH1];
  __shared__ alignas(16) short bw_lds[256 * BW_PITCH1];
  __shared__ alignas(16) short phi_lds[64 * PHI_PITCH1];
  __shared__ float xsq[64];
  __shared__ float csq[256];

  const int tid = threadIdx.x;
  const int lane = tid & 63;
  const int wv = tid >> 6;
  const int lm = lane & 15;
  const int lg = lane >> 4;
  const int m0 = blockIdx.x * 64;
  const float gma = gamma_p[0];

  {
    const int row = tid >> 2;
    const int seg = tid & 3;
    const float* xr = x + (size_t)(m0 + row) * NF + seg * 128;
    short* ar = a_lds + row * A_PITCH1 + seg * 128;
    float xp = 0.f;
#pragma unroll
    for (int i = 0; i < 32; ++i) {
      f4 v = ((const f4*)xr)[i];
      xp += v.x * v.x + v.y * v.y + v.z * v.z + v.w * v.w;
      short4v h;
      h.x = bf16t(v.x); h.y = bf16t(v.y); h.z = bf16t(v.z); h.w = bf16t(v.w);
      *(short4v*)(ar + i * 4) = h;
    }
    ((float*)phi_lds)[tid] = xp;
  }
  __syncthreads();
  if (tid < 64) {
    const float* pp = (const float*)phi_lds;
    xsq[tid] = pp[tid * 4] + pp[tid * 4 + 1] + pp[tid * 4 + 2] + pp[tid * 4 + 3];
  }

  const f4 fzero = {0.f, 0.f, 0.f, 0.f};
  f4 acc2[4][2];
#pragma unroll
  for (int i = 0; i < 4; ++i)
#pragma unroll
    for (int n = 0; n < 2; ++n) acc2[i][n] = fzero;

  const short* a_base = a_lds + lm * A_PITCH1 + lg * 8;
  const short* b_base = bw_lds + (64 * wv + lm) * BW_PITCH1 + lg * 8;
  const short* w_base = bw_lds + lm * BW_PITCH1 + lg * 8;
  const short* p_base = phi_lds + lm * PHI_PITCH1 + lg * 8;

  for (int chunk = 0; chunk < 4; ++chunk) {
    const int c0 = chunk * 256;
    f4 acc1[4][4];
#pragma unroll
    for (int i = 0; i < 4; ++i)
#pragma unroll
      for (int t = 0; t < 4; ++t) acc1[i][t] = fzero;
    float cpriv = 0.f;

    for (int kb = 0; kb < 8; ++kb) {
      __syncthreads();
      {
        const float* cr = ctr + (size_t)(c0 + tid) * NF + kb * 64;
        short* br = bw_lds + tid * BW_PITCH1;
#pragma unroll
        for (int i = 0; i < 16; ++i) {
          f4 v = ((const f4*)cr)[i];
          cpriv += v.x * v.x + v.y * v.y + v.z * v.z + v.w * v.w;
          short4v h;
          h.x = bf16t(v.x); h.y = bf16t(v.y); h.z = bf16t(v.z); h.w = bf16t(v.w);
          *(short4v*)(br + i * 4) = h;
        }
      }
      __syncthreads();
#pragma unroll
      for (int s = 0; s < 2; ++s) {
        short8 av[4], bv8[4];
#pragma unroll
        for (int i = 0; i < 4; ++i)
          av[i] = *(const short8*)(a_base + 16 * i * A_PITCH1 + 64 * kb + 32 * s);
#pragma unroll
        for (int t = 0; t < 4; ++t)
          bv8[t] = *(const short8*)(b_base + 16 * t * BW_PITCH1 + 32 * s);
#pragma unroll
        for (int i = 0; i < 4; ++i)
#pragma unroll
          for (int t = 0; t < 4; ++t)
            acc1[i][t] = __builtin_amdgcn_mfma_f32_16x16x32_bf16(
                av[i], bv8[t], acc1[i][t], 0, 0, 0);
      }
    }

    csq[tid] = cpriv;
    __syncthreads();

#pragma unroll
    for (int i = 0; i < 4; ++i) {
#pragma unroll
      for (int t = 0; t < 4; ++t) {
        const int colL = 64 * wv + 16 * t + lm;
        const float cs = csq[colL];
#pragma unroll
        for (int r = 0; r < 4; ++r) {
          const int rowL = 16 * i + 4 * lg + r;
          float d2 = xsq[rowL] + cs - 2.0f * acc1[i][t][r];
          d2 = fmaxf(d2, 0.f);
          const float ph = __expf(-gma * __fsqrt_rn(d2));
          phi_lds[rowL * PHI_PITCH1 + colL] = bf16t(ph);
        }
      }
    }

    for (int u = 0; u < 4; ++u) {
      __syncthreads();
      {
        const int row = tid >> 1;
        const int half = tid & 1;
        short* wr = bw_lds + row * BW_PITCH1 + half * 32;
        if (row < NK) {
          const float* ws = W + (size_t)row * NC + c0 + u * 64 + half * 32;
#pragma unroll
          for (int i = 0; i < 8; ++i) {
            f4 v = ((const f4*)ws)[i];
            short4v h;
            h.x = bf16t(v.x); h.y = bf16t(v.y); h.z = bf16t(v.z); h.w = bf16t(v.w);
            *(short4v*)(wr + i * 4) = h;
          }
        } else {
          const short4v zz = {0, 0, 0, 0};
#pragma unroll
          for (int i = 0; i < 8; ++i) *(short4v*)(wr + i * 4) = zz;
        }
      }
      __syncthreads();
#pragma unroll
      for (int s = 0; s < 2; ++s) {
        short8 pv[4], wv8[2];
#pragma unroll
        for (int i = 0; i < 4; ++i)
          pv[i] = *(const short8*)(p_base + 16 * i * PHI_PITCH1 + 64 * u + 32 * s);
#pragma unroll
        for (int n = 0; n < 2; ++n)
          wv8[n] = *(const short8*)(w_base + 16 * (2 * wv + n) * BW_PITCH1 + 32 * s);
#pragma unroll
        for (int i = 0; i < 4; ++i)
#pragma unroll
          for (int n = 0; n < 2; ++n)
            acc2[i][n] = __builtin_amdgcn_mfma_f32_16x16x32_bf16(
                pv[i], wv8[n], acc2[i][n], 0, 0, 0);
      }
    }
  }

#pragma unroll
  for (int i = 0; i < 4; ++i) {
#pragma unroll
    for (int n = 0; n < 2; ++n) {
      const int kout = 32 * wv + 16 * n + lm;
      if (kout < NK) {
        const float bb = bvec[kout];
#pragma unroll
        for (int r = 0; r < 4; ++r) {
          const int row = m0 + 16 * i + 4 * lg + r;
          out[(size_t)row * NK + kout] = acc2[i][n][r] + bb;
        }
      }
    }
  }
}

extern "C" void kernel_launch(void* const* d_in, const int* in_sizes, int n_in,
                              void* d_out, int out_size, void* d_ws, size_t ws_size,
                              hipStream_t stream) {
  (void)in_sizes; (void)n_in; (void)out_size;
  const float* x       = (const float*)d_in[0];
  const float* centers = (const float*)d_in[1];
  const float* gamma   = (const float*)d_in[2];
  const float* W       = (const float*)d_in[3];
  const float* b       = (const float*)d_in[4];
  float* out = (float*)d_out;

  if (ws_size >= (size_t)WS_NEED) {
    char* wsb = (char*)d_ws;
    char*  cbp  = wsb;                                  // 512KB fp8 centers
    float* csqp = (float*)(wsb + CB_BYTES);             // 1024 f32
    char*  wbp  = wsb + CB_BYTES + NC * 4;              // 256KB bf16 W
    prep_all<<<dim3(34), dim3(256), 0, stream>>>(centers, W, cbp, csqp, wbp);
    rbf_main<<<dim3(NB / 32), dim3(256), 0, stream>>>(x, cbp, csqp, wbp, b,
                                                      gamma, out);
  } else {
    rbf_fused_v1<<<dim3(NB / 64), dim3(256), 0, stream>>>(x, centers, gamma, W,
                                                          b, out);
  }
}